// Round 1
// baseline (14494.455 us; speedup 1.0000x reference)
//
#include <hip/hip_runtime.h>
#include <hip/hip_cooperative_groups.h>
#include <math.h>

namespace cg = cooperative_groups;

// Problem dims
#define NB 16
#define NP 196
#define NE 1024
#define NA 1024
#define ND 512
#define NEMB 512
#define NV 10000
#define NL 32
#define NT 31
#define NG 2048  // 4*D

// d_out float offsets (outputs concatenated flat in return order)
#define OFF_PRED    0
#define OFF_CAPS    4960000
#define OFF_DECLEN  4960512
#define OFF_ALPHAS  4960528
#define OFF_SORTIND 5057744

// Scratch aliased into d_out's predictions region (dead before fc GEMM runs)
#define OFF_ATT1    0         // 16*196*1024 = 3,211,264 floats
#define OFF_PREIH   3211264   // 31*16*2048  = 1,015,808 floats (end 4,227,072 < 4,960,000)

// Workspace float offsets
#define WS_H      32
#define WS_C      8224
#define WS_MEAN   16416
#define WS_M1     32800      // [b][4096]: att2 | gate(sigmoided) | gates_h
#define WS_SCORES 98336
#define WS_AWEG   101536
#define WS_HHIST  117920     // [t][b][d], 253,952 floats

__device__ __forceinline__ float sigf(float x){ return 1.0f/(1.0f+expf(-x)); }

// ---------------- sort + small outputs ----------------
__global__ void k_sort(const int* __restrict__ caplen, const int* __restrict__ caps,
                       int* __restrict__ wsi, float* __restrict__ out){
  __shared__ int sidx[NB];
  int tid = threadIdx.x;
  if (tid == 0){
    int len[NB], idx[NB];
    for (int i=0;i<NB;i++){ len[i]=caplen[i]; idx[i]=i; }
    // stable descending insertion sort (== argsort(-len, stable))
    for (int i=1;i<NB;i++){
      int key=idx[i]; int kl=len[key]; int j=i-1;
      while (j>=0 && len[idx[j]]<kl){ idx[j+1]=idx[j]; j--; }
      idx[j+1]=key;
    }
    for (int b=0;b<NB;b++){
      sidx[b]=idx[b];
      wsi[b]=idx[b];
      int dl = len[idx[b]]-1;
      wsi[NB+b]=dl;
      out[OFF_DECLEN+b]=(float)dl;
      out[OFF_SORTIND+b]=(float)idx[b];
    }
  }
  __syncthreads();
  for (int x=tid; x<NB*NL; x+=blockDim.x){
    int b = x>>5, l = x&31;
    out[OFF_CAPS + x] = (float)caps[sidx[b]*NL + l];
  }
}

// ---------------- mean over P ----------------
__global__ __launch_bounds__(256) void k_mean(const float* __restrict__ enc,
                                              const int* __restrict__ wsi,
                                              float* __restrict__ wsf){
  int gid = blockIdx.x*256 + threadIdx.x;   // 16384 = 16*1024
  int b = gid>>10, e = gid&1023;
  int ob = wsi[b];
  const float* p = enc + (size_t)ob*NP*NE + e;
  float s = 0.f;
  for (int i=0;i<NP;i++) s += p[(size_t)i*NE];
  wsf[WS_MEAN + b*NE + e] = s*(1.0f/196.0f);
}

// ---------------- h0/c0 init ----------------
__global__ __launch_bounds__(256) void k_init(const float* __restrict__ ihW, const float* __restrict__ ihb,
                                              const float* __restrict__ icW, const float* __restrict__ icb,
                                              float* __restrict__ wsf){
  int gid = blockIdx.x*256 + threadIdx.x;   // 16384 = 16*1024
  int b = gid>>10, x = gid&1023;
  int d = x&511, which = x>>9;
  const float* W = which ? icW : ihW;
  const float* mp = wsf + WS_MEAN + b*NE;
  float s = which ? icb[d] : ihb[d];
  for (int e=0;e<NE;e++) s = fmaf(mp[e], W[(size_t)e*ND + d], s);
  wsf[(which?WS_C:WS_H) + b*ND + d] = s;
}

// ---------------- generic tiled fp32 GEMM ----------------
// mode 0: att1  A=encoder_out gathered by (sort_ind,p), bias1=enc_att_b, out[m*N+n]
// mode 1: preih A=emb gathered by caps_s,              bias1=b_ih, bias2=b_hh, out[m*N+n]
// mode 2: fc    A=h_hist plain, bias1=fc_b, out remapped [b][t][n], masked by declen
__global__ __launch_bounds__(256) void k_gemm(const float* __restrict__ Abase,
                                              const float* __restrict__ Bmat,
                                              const float* __restrict__ bias1,
                                              const float* __restrict__ bias2,
                                              float* __restrict__ out,
                                              int M, int N, int K, int mode,
                                              const int* __restrict__ wsi,
                                              const int* __restrict__ caps){
  __shared__ float As[16*64];
  __shared__ float Bs[16*64];
  int tid = threadIdx.x;
  int n0 = blockIdx.x*64, m0 = blockIdx.y*64;
  int tx = tid&15, ty = tid>>4;
  float acc[4][4] = {};
  int r = tid>>2, kq = tid&3;   // A loader: row r, k-quad kq
  int kk = tid>>4, nq = tid&15; // B loader
  int row = m0 + r;
  const float* arow = nullptr;
  if (row < M){
    if (mode==0){ int b=row/196, p=row%196; arow = Abase + (size_t)(wsi[b]*196 + p)*NE; }
    else if (mode==1){ int t=row>>4, b=row&15; int cap = caps[wsi[b]*NL + t]; arow = Abase + (size_t)cap*NEMB; }
    else { arow = Abase + (size_t)row*ND; }
  }
  int ktiles = K>>4;
  for (int kt=0; kt<ktiles; kt++){
    int k0 = kt<<4;
    float4 av = make_float4(0.f,0.f,0.f,0.f);
    if (arow) av = *(const float4*)(arow + k0 + kq*4);
    As[(kq*4+0)*64 + r] = av.x;
    As[(kq*4+1)*64 + r] = av.y;
    As[(kq*4+2)*64 + r] = av.z;
    As[(kq*4+3)*64 + r] = av.w;
    int ncol = n0 + nq*4;
    const float* bp = Bmat + (size_t)(k0+kk)*N + ncol;
    float4 bv;
    if (ncol+3 < N) bv = *(const float4*)bp;
    else {
      bv.x = (ncol+0<N)?bp[0]:0.f; bv.y = (ncol+1<N)?bp[1]:0.f;
      bv.z = (ncol+2<N)?bp[2]:0.f; bv.w = (ncol+3<N)?bp[3]:0.f;
    }
    *((float4*)&Bs[kk*64 + nq*4]) = bv;
    __syncthreads();
    #pragma unroll
    for (int k=0;k<16;k++){
      const float4 a = *(const float4*)(&As[k*64 + ty*4]);
      const float4 b = *(const float4*)(&Bs[k*64 + tx*4]);
      float ar[4] = {a.x,a.y,a.z,a.w};
      float br[4] = {b.x,b.y,b.z,b.w};
      #pragma unroll
      for (int i=0;i<4;i++)
        #pragma unroll
        for (int j=0;j<4;j++)
          acc[i][j] = fmaf(ar[i], br[j], acc[i][j]);
    }
    __syncthreads();
  }
  if (mode == 2){
    #pragma unroll
    for (int i=0;i<4;i++){
      int m = m0 + ty*4 + i;
      if (m >= M) continue;
      int b = m & 15, t = m >> 4;
      bool act = wsi[NB + b] > t;
      size_t obase = (size_t)b*NT*NV + (size_t)t*NV;
      #pragma unroll
      for (int j=0;j<4;j++){
        int n = n0 + tx*4 + j;
        if (n >= N) continue;
        out[obase + n] = act ? (acc[i][j] + bias1[n]) : 0.0f;
      }
    }
  } else {
    #pragma unroll
    for (int i=0;i<4;i++){
      int m = m0 + ty*4 + i;
      if (m >= M) continue;
      #pragma unroll
      for (int j=0;j<4;j++){
        int n = n0 + tx*4 + j;
        if (n >= N) continue;
        float v = acc[i][j] + bias1[n];
        if (bias2) v += bias2[n];
        out[(size_t)m*N + n] = v;
      }
    }
  }
}

// ---------------- the sequential scan (cooperative, grid must be exactly 128) ----------------
struct ScanParams {
  float* wsf;
  const int* wsi;
  const float* att1;
  const float* preih;
  const float* dec_att_W;
  const float* dec_att_b;
  const float* f_beta_W;
  const float* f_beta_b;
  const float* W_hh;
  const float* W_ih;
  const float* full_att_W;
  const float* full_att_b;
  const float* enc;
  float* out;
};

__global__ __launch_bounds__(256) void k_scan(ScanParams P){
  cg::grid_group gg = cg::this_grid();
  __shared__ float smem[4608];
  const int tid = threadIdx.x;
  const int bx = blockIdx.x;     // gridDim.x == 128 (hard assumption)
  const int lane = tid & 63;
  const int wid = tid >> 6;
  float* h      = P.wsf + WS_H;
  float* c      = P.wsf + WS_C;
  float* M1     = P.wsf + WS_M1;
  float* scores = P.wsf + WS_SCORES;
  float* aweg   = P.wsf + WS_AWEG;
  float* hhist  = P.wsf + WS_HHIST;
  const int* sortind = P.wsi;
  const int* declen  = P.wsi + NB;

  for (int t=0; t<NT; t++){
    // -- Phase A: M1[b][0:4096] = h @ [dec_att_W | f_beta_W | W_hh] (+bias / sigmoid on gate)
    {
      const int jsl = bx & 31, bg = bx >> 5;   // 32 col-slices x 4 b-groups
      const int j0 = jsl * 128;
      for (int x=tid; x<2048; x+=256)
        smem[x] = h[(bg*4 + (x>>9))*ND + (x&511)];
      __syncthreads();
      const int jl = tid & 127, bb = tid >> 7;
      const int j = j0 + jl;
      const int b1 = bg*4 + bb*2;
      const float* hs0 = smem + (bb*2)*ND;
      const float* hs1 = hs0 + ND;
      const float* Wcol; int ld;
      if (j < 1024){ Wcol = P.dec_att_W + j; ld = 1024; }
      else if (j < 2048){ Wcol = P.f_beta_W + (j - 1024); ld = 1024; }
      else { Wcol = P.W_hh + (j - 2048); ld = 2048; }
      float a0 = 0.f, a1 = 0.f;
      for (int k=0;k<ND;k++){
        float w = Wcol[(size_t)k*ld];
        a0 = fmaf(hs0[k], w, a0);
        a1 = fmaf(hs1[k], w, a1);
      }
      float v0, v1;
      if (j < 1024){ float bs = P.dec_att_b[j]; v0 = a0+bs; v1 = a1+bs; }
      else if (j < 2048){ float bs = P.f_beta_b[j-1024]; v0 = sigf(a0+bs); v1 = sigf(a1+bs); }
      else { v0 = a0; v1 = a1; }
      M1[b1*4096 + j] = v0;
      M1[(b1+1)*4096 + j] = v1;
    }
    gg.sync();
    // -- Phase B: scores[b][p] = relu(att1[b,p,:] + att2[b,:]) . full_att_W + full_att_b
    {
      const float fab = P.full_att_b[0];
      for (int o = bx*4 + wid; o < NB*NP; o += 512){
        const int b = o / NP;
        const float* a1p = P.att1 + (size_t)o * NE;    // o == b*196+p
        const float* a2p = M1 + b*4096;
        float s = 0.f;
        for (int e = lane; e < NE; e += 64){
          float v = a1p[e] + a2p[e];
          v = v > 0.f ? v : 0.f;
          s = fmaf(v, P.full_att_W[e], s);
        }
        #pragma unroll
        for (int off=32; off; off>>=1) s += __shfl_down(s, off, 64);
        if (lane == 0) scores[o] = s + fab;
      }
    }
    gg.sync();
    // -- Phase C: softmax over p, awe, awe_g = gate + awe, alphas output
    {
      float* sc  = smem;
      float* red = smem + 256;
      for (int task = bx; task < 256; task += 128){
        const int b = task >> 4, sl = task & 15;
        const int ob = sortind[b];
        float v = (tid < NP) ? scores[b*NP + tid] : -1e30f;
        sc[tid] = v; red[tid] = v;
        __syncthreads();
        for (int s=128; s; s>>=1){ if (tid < s) red[tid] = fmaxf(red[tid], red[tid+s]); __syncthreads(); }
        const float mx = red[0];
        __syncthreads();
        float ex = (tid < NP) ? expf(sc[tid] - mx) : 0.f;
        sc[tid] = ex; red[tid] = ex;
        __syncthreads();
        for (int s=128; s; s>>=1){ if (tid < s) red[tid] += red[tid+s]; __syncthreads(); }
        const float inv = 1.f / red[0];
        __syncthreads();
        sc[tid] *= inv;            // alpha in sc[0:196]
        __syncthreads();
        const int eoff = tid & 63, ch = tid >> 6;
        const int e = sl*64 + eoff;
        const float* ep = P.enc + (size_t)ob*NP*NE + e;
        float partial = 0.f;
        for (int i=0;i<49;i++){
          int p = ch*49 + i;       // 4*49 == 196 exactly
          partial = fmaf(ep[(size_t)p*NE], sc[p], partial);
        }
        red[ch*64 + eoff] = partial;
        __syncthreads();
        if (tid < 64){
          float aw = red[tid] + red[64+tid] + red[128+tid] + red[192+tid];
          aweg[b*1024 + sl*64 + tid] = M1[b*4096 + 1024 + sl*64 + tid] + aw;
        }
        if (sl == 0 && tid < NP){
          P.out[OFF_ALPHAS + (size_t)b*NT*NP + (size_t)t*NP + tid] = (declen[b] > t) ? sc[tid] : 0.f;
        }
        __syncthreads();
      }
    }
    gg.sync();
    // -- Phase D: gates = pre_ih + gates_h + awe_g @ W_ih[512:], LSTM pointwise, state update
    if (bx < 64){
      float* ag = smem;
      float* gl = smem + 4096;
      const int bg = bx >> 4, dsl = bx & 15, d0 = dsl*32;
      for (int x=tid; x<4096; x+=256)
        ag[x] = aweg[(bg*4 + (x>>10))*1024 + (x & 1023)];
      __syncthreads();
      const int jl = tid & 127, bb = tid >> 7;
      const int gi = jl >> 5, dd = jl & 31;
      const int j = gi*512 + d0 + dd;
      const int b1 = bg*4 + bb*2;
      float a0 = P.preih[(size_t)(t*NB + b1)*NG + j]     + M1[b1*4096 + 2048 + j];
      float a1 = P.preih[(size_t)(t*NB + b1 + 1)*NG + j] + M1[(b1+1)*4096 + 2048 + j];
      const float* ag0 = ag + (bb*2)*1024;
      const float* ag1 = ag0 + 1024;
      const float* Wc = P.W_ih + (size_t)512*NG + j;
      for (int k=0;k<1024;k++){
        float w = Wc[(size_t)k*NG];
        a0 = fmaf(ag0[k], w, a0);
        a1 = fmaf(ag1[k], w, a1);
      }
      gl[(bb*2)*128 + jl] = a0;
      gl[(bb*2+1)*128 + jl] = a1;
      __syncthreads();
      if (tid < 128){
        const int bi = tid >> 5, dd2 = tid & 31;
        const int b = bg*4 + bi, d = d0 + dd2;
        const float gI = gl[bi*128 + dd2];
        const float gF = gl[bi*128 + 32 + dd2];
        const float gG = gl[bi*128 + 64 + dd2];
        const float gO = gl[bi*128 + 96 + dd2];
        const float co = c[b*ND + d];
        const float cn = sigf(gF)*co + sigf(gI)*tanhf(gG);
        const float hn = sigf(gO)*tanhf(cn);
        hhist[(size_t)(t*NB + b)*ND + d] = hn;
        if (declen[b] > t){ h[b*ND + d] = hn; c[b*ND + d] = cn; }
      }
    }
    gg.sync();
  }
}

extern "C" void kernel_launch(void* const* d_in, const int* in_sizes, int n_in,
                              void* d_out, int out_size, void* d_ws, size_t ws_size,
                              hipStream_t stream) {
  const float* encoder_out = (const float*)d_in[0];
  const float* enc_att_W   = (const float*)d_in[1];
  const float* enc_att_b   = (const float*)d_in[2];
  const float* dec_att_W   = (const float*)d_in[3];
  const float* dec_att_b   = (const float*)d_in[4];
  const float* full_att_W  = (const float*)d_in[5];
  const float* full_att_b  = (const float*)d_in[6];
  const float* emb         = (const float*)d_in[7];
  const float* W_ih        = (const float*)d_in[8];
  const float* b_ih        = (const float*)d_in[9];
  const float* W_hh        = (const float*)d_in[10];
  const float* b_hh        = (const float*)d_in[11];
  const float* init_h_W    = (const float*)d_in[12];
  const float* init_h_b    = (const float*)d_in[13];
  const float* init_c_W    = (const float*)d_in[14];
  const float* init_c_b    = (const float*)d_in[15];
  const float* f_beta_W    = (const float*)d_in[16];
  const float* f_beta_b    = (const float*)d_in[17];
  const float* fc_W        = (const float*)d_in[18];
  const float* fc_b        = (const float*)d_in[19];
  const int*   caps        = (const int*)d_in[20];
  const int*   caplen      = (const int*)d_in[21];
  (void)in_sizes; (void)n_in; (void)out_size; (void)ws_size;

  float* out  = (float*)d_out;
  float* wsf  = (float*)d_ws;
  int*   wsi  = (int*)d_ws;
  float* att1F  = out + OFF_ATT1;
  float* preihF = out + OFF_PREIH;

  hipLaunchKernelGGL(k_sort, dim3(1), dim3(64), 0, stream, caplen, caps, wsi, out);
  hipLaunchKernelGGL(k_mean, dim3(64), dim3(256), 0, stream, encoder_out, wsi, wsf);
  hipLaunchKernelGGL(k_init, dim3(64), dim3(256), 0, stream, init_h_W, init_h_b, init_c_W, init_c_b, wsf);
  // att1 = enc_s @ enc_att_W + enc_att_b : M=3136, N=1024, K=1024
  hipLaunchKernelGGL(k_gemm, dim3(16,49), dim3(256), 0, stream,
                     encoder_out, enc_att_W, enc_att_b, (const float*)nullptr,
                     att1F, 3136, 1024, 1024, 0, wsi, caps);
  // pre_ih = embs @ W_ih[:512] + b_ih + b_hh : M=496, N=2048, K=512
  hipLaunchKernelGGL(k_gemm, dim3(32,8), dim3(256), 0, stream,
                     emb, W_ih, b_ih, b_hh,
                     preihF, 496, 2048, 512, 1, wsi, caps);

  ScanParams sp;
  sp.wsf = wsf; sp.wsi = wsi;
  sp.att1 = att1F; sp.preih = preihF;
  sp.dec_att_W = dec_att_W; sp.dec_att_b = dec_att_b;
  sp.f_beta_W = f_beta_W; sp.f_beta_b = f_beta_b;
  sp.W_hh = W_hh; sp.W_ih = W_ih;
  sp.full_att_W = full_att_W; sp.full_att_b = full_att_b;
  sp.enc = encoder_out; sp.out = out;
  void* args[] = { &sp };
  hipLaunchCooperativeKernel((void*)k_scan, dim3(128), dim3(256), args, 0, stream);

  // predictions = h_hist @ fc_W + fc_b (masked) : M=496, N=10000, K=512
  hipLaunchKernelGGL(k_gemm, dim3(157,8), dim3(256), 0, stream,
                     wsf + WS_HHIST, fc_W, fc_b, (const float*)nullptr,
                     out, 496, 10000, 512, 2, wsi, caps);
}

// Round 3
// 5512.416 us; speedup vs baseline: 2.6294x; 2.6294x over previous
//
#include <hip/hip_runtime.h>
#include <hip/hip_cooperative_groups.h>
#include <math.h>

namespace cg = cooperative_groups;

// Problem dims
#define NB 16
#define NP 196
#define NE 1024
#define NA 1024
#define ND 512
#define NEMB 512
#define NV 10000
#define NL 32
#define NT 31
#define NG 2048  // 4*D

#define NBLK 256   // cooperative grid == CU count (proven-safe regime)

// d_out float offsets (outputs concatenated flat in return order)
#define OFF_PRED    0
#define OFF_CAPS    4960000
#define OFF_DECLEN  4960512
#define OFF_ALPHAS  4960528
#define OFF_SORTIND 5057744

// Scratch aliased into d_out's predictions region (dead before fc GEMM runs)
#define OFF_ATT1    0         // 16*196*1024 = 3,211,264 floats
#define OFF_PREIH   3211264   // 31*16*2048  = 1,015,808 floats (end 4,227,072)
#define OFF_GSUM    4227072   // 16*2048     = 32,768 floats (end 4,259,840 < 4,960,000)

// Workspace float offsets
#define WS_H      32
#define WS_C      8224
#define WS_MEAN   16416
#define WS_M1     32800      // [b][4096]: att2 | gate(sigmoided) | gates_h
#define WS_SCORES 98336
#define WS_AWEG   101536
#define WS_HHIST  117920     // [t][b][d], 253,952 floats

__device__ __forceinline__ float sigf(float x){ return 1.0f/(1.0f+expf(-x)); }

// ---------------- sort + small outputs ----------------
__global__ void k_sort(const int* __restrict__ caplen, const int* __restrict__ caps,
                       int* __restrict__ wsi, float* __restrict__ out){
  __shared__ int sidx[NB];
  int tid = threadIdx.x;
  if (tid == 0){
    int len[NB], idx[NB];
    for (int i=0;i<NB;i++){ len[i]=caplen[i]; idx[i]=i; }
    for (int i=1;i<NB;i++){
      int key=idx[i]; int kl=len[key]; int j=i-1;
      while (j>=0 && len[idx[j]]<kl){ idx[j+1]=idx[j]; j--; }
      idx[j+1]=key;
    }
    for (int b=0;b<NB;b++){
      sidx[b]=idx[b];
      wsi[b]=idx[b];
      int dl = len[idx[b]]-1;
      wsi[NB+b]=dl;
      out[OFF_DECLEN+b]=(float)dl;
      out[OFF_SORTIND+b]=(float)idx[b];
    }
  }
  __syncthreads();
  for (int x=tid; x<NB*NL; x+=blockDim.x){
    int b = x>>5, l = x&31;
    out[OFF_CAPS + x] = (float)caps[sidx[b]*NL + l];
  }
}

// ---------------- mean over P ----------------
__global__ __launch_bounds__(256) void k_mean(const float* __restrict__ enc,
                                              const int* __restrict__ wsi,
                                              float* __restrict__ wsf){
  int gid = blockIdx.x*256 + threadIdx.x;   // 16384 = 16*1024
  int b = gid>>10, e = gid&1023;
  int ob = wsi[b];
  const float* p = enc + (size_t)ob*NP*NE + e;
  float s = 0.f;
  for (int i=0;i<NP;i++) s += p[(size_t)i*NE];
  wsf[WS_MEAN + b*NE + e] = s*(1.0f/196.0f);
}

// ---------------- h0/c0 init ----------------
__global__ __launch_bounds__(256) void k_init(const float* __restrict__ ihW, const float* __restrict__ ihb,
                                              const float* __restrict__ icW, const float* __restrict__ icb,
                                              float* __restrict__ wsf){
  int gid = blockIdx.x*256 + threadIdx.x;   // 16384 = 16*1024
  int b = gid>>10, x = gid&1023;
  int d = x&511, which = x>>9;
  const float* W = which ? icW : ihW;
  const float* mp = wsf + WS_MEAN + b*NE;
  float s = which ? icb[d] : ihb[d];
  for (int e=0;e<NE;e++) s = fmaf(mp[e], W[(size_t)e*ND + d], s);
  wsf[(which?WS_C:WS_H) + b*ND + d] = s;
}

// ---------------- generic tiled fp32 GEMM ----------------
__global__ __launch_bounds__(256) void k_gemm(const float* __restrict__ Abase,
                                              const float* __restrict__ Bmat,
                                              const float* __restrict__ bias1,
                                              const float* __restrict__ bias2,
                                              float* __restrict__ out,
                                              int M, int N, int K, int mode,
                                              const int* __restrict__ wsi,
                                              const int* __restrict__ caps){
  __shared__ float As[16*64];
  __shared__ float Bs[16*64];
  int tid = threadIdx.x;
  int n0 = blockIdx.x*64, m0 = blockIdx.y*64;
  int tx = tid&15, ty = tid>>4;
  float acc[4][4] = {};
  int r = tid>>2, kq = tid&3;
  int kk = tid>>4, nq = tid&15;
  int row = m0 + r;
  const float* arow = nullptr;
  if (row < M){
    if (mode==0){ int b=row/196, p=row%196; arow = Abase + (size_t)(wsi[b]*196 + p)*NE; }
    else if (mode==1){ int t=row>>4, b=row&15; int cap = caps[wsi[b]*NL + t]; arow = Abase + (size_t)cap*NEMB; }
    else { arow = Abase + (size_t)row*ND; }
  }
  int ktiles = K>>4;
  for (int kt=0; kt<ktiles; kt++){
    int k0 = kt<<4;
    float4 av = make_float4(0.f,0.f,0.f,0.f);
    if (arow) av = *(const float4*)(arow + k0 + kq*4);
    As[(kq*4+0)*64 + r] = av.x;
    As[(kq*4+1)*64 + r] = av.y;
    As[(kq*4+2)*64 + r] = av.z;
    As[(kq*4+3)*64 + r] = av.w;
    int ncol = n0 + nq*4;
    const float* bp = Bmat + (size_t)(k0+kk)*N + ncol;
    float4 bv;
    if (ncol+3 < N) bv = *(const float4*)bp;
    else {
      bv.x = (ncol+0<N)?bp[0]:0.f; bv.y = (ncol+1<N)?bp[1]:0.f;
      bv.z = (ncol+2<N)?bp[2]:0.f; bv.w = (ncol+3<N)?bp[3]:0.f;
    }
    *((float4*)&Bs[kk*64 + nq*4]) = bv;
    __syncthreads();
    #pragma unroll
    for (int k=0;k<16;k++){
      const float4 a = *(const float4*)(&As[k*64 + ty*4]);
      const float4 b = *(const float4*)(&Bs[k*64 + tx*4]);
      float ar[4] = {a.x,a.y,a.z,a.w};
      float br[4] = {b.x,b.y,b.z,b.w};
      #pragma unroll
      for (int i=0;i<4;i++)
        #pragma unroll
        for (int j=0;j<4;j++)
          acc[i][j] = fmaf(ar[i], br[j], acc[i][j]);
    }
    __syncthreads();
  }
  if (mode == 2){
    #pragma unroll
    for (int i=0;i<4;i++){
      int m = m0 + ty*4 + i;
      if (m >= M) continue;
      int b = m & 15, t = m >> 4;
      bool act = wsi[NB + b] > t;
      size_t obase = (size_t)b*NT*NV + (size_t)t*NV;
      #pragma unroll
      for (int j=0;j<4;j++){
        int n = n0 + tx*4 + j;
        if (n >= N) continue;
        out[obase + n] = act ? (acc[i][j] + bias1[n]) : 0.0f;
      }
    }
  } else {
    #pragma unroll
    for (int i=0;i<4;i++){
      int m = m0 + ty*4 + i;
      if (m >= M) continue;
      #pragma unroll
      for (int j=0;j<4;j++){
        int n = n0 + tx*4 + j;
        if (n >= N) continue;
        float v = acc[i][j] + bias1[n];
        if (bias2) v += bias2[n];
        out[(size_t)m*N + n] = v;
      }
    }
  }
}

// ---------------- persistent cooperative scan, 256 blocks x 512 threads ----------------
struct ScanParams {
  float* wsf;
  const int* wsi;
  const float* att1;
  const float* preih;
  float* gsum;
  const float* dec_att_W;
  const float* dec_att_b;
  const float* f_beta_W;
  const float* f_beta_b;
  const float* W_hh;
  const float* W_ih;
  const float* full_att_W;
  const float* full_att_b;
  const float* enc;
  float* out;
};

__global__ __launch_bounds__(512) void k_scan(ScanParams P){
  cg::grid_group gg = cg::this_grid();
  __shared__ __align__(16) float hs[4*516];     // persistent h for this block's 4 batches
  __shared__ __align__(16) float cs[4*516];     // persistent c
  __shared__ __align__(16) float scratch[6272]; // phase-local
  const int tid = threadIdx.x;
  const int bx = blockIdx.x;           // [0, 256)
  const int lane = tid & 63;
  const int wid = tid >> 6;            // [0,8)
  const int bg = bx >> 6;              // 4 batch-groups of 4 batches
  const int jt = bx & 63;              // 64 column tiles
  const bool leader = (jt == 0);

  float* M1     = P.wsf + WS_M1;
  float* scores = P.wsf + WS_SCORES;
  float* aweg   = P.wsf + WS_AWEG;
  float* hhist  = P.wsf + WS_HHIST;
  const int* sortind = P.wsi;
  const int* declen  = P.wsi + NB;

  // Phase A tile setup (block-uniform): 64 output cols per tile
  const float* Wa; int lda, jbaseA, modeA;
  if (jt < 16){ Wa = P.dec_att_W; lda = 1024; jbaseA = jt*64; modeA = 0; }
  else if (jt < 32){ Wa = P.f_beta_W; lda = 1024; jbaseA = (jt-16)*64; modeA = 1; }
  else { Wa = P.W_hh; lda = 2048; jbaseA = (jt-32)*64; modeA = 2; }
  const float* Wih2 = P.W_ih + (size_t)512*NG;

  for (int tt=0; tt<=NT; tt++){
    // ---- preamble: establish h(tt), c(tt) in LDS; emit hhist[tt-1]
    if (tt == 0){
      const float* h0 = P.wsf + WS_H;
      const float* c0 = P.wsf + WS_C;
      #pragma unroll
      for (int i=0;i<4;i++){
        int idx = tid + i*512;          // [0,2048)
        int bl = idx >> 9, d = idx & 511;
        int B = bg*4 + bl;
        hs[bl*516 + d] = h0[B*ND + d];
        cs[bl*516 + d] = c0[B*ND + d];
      }
    } else {
      #pragma unroll
      for (int i=0;i<4;i++){
        int idx = tid + i*512;
        int bl = idx >> 9, d = idx & 511;
        int B = bg*4 + bl;
        const float* gp = P.gsum + B*NG;
        float gi = gp[d], gf = gp[512+d], gG = gp[1024+d], go = gp[1536+d];
        float co = cs[bl*516 + d];
        float cn = sigf(gf)*co + sigf(gi)*tanhf(gG);
        float hn = sigf(go)*tanhf(cn);
        if (leader) hhist[(size_t)((tt-1)*NB + B)*ND + d] = hn;
        if (declen[B] > (tt-1)){ hs[bl*516 + d] = hn; cs[bl*516 + d] = cn; }
      }
    }
    __syncthreads();
    if (tt == NT) break;

    // ---- Phase A: M1[B][jout] = h . W  (att2 | sigmoided gate | gates_h)
    {
      const int jq = tid & 15, bl = (tid>>4)&3, kp = tid>>6;
      const float* wp = Wa + (size_t)(kp*64)*lda + jbaseA + jq*4;
      const float* hp = hs + bl*516 + kp*64;
      float4 acc = make_float4(0.f,0.f,0.f,0.f);
      #pragma unroll
      for (int k4=0;k4<16;k4++){
        float4 w0 = *(const float4*)(wp);
        float4 w1 = *(const float4*)(wp + lda);
        float4 w2 = *(const float4*)(wp + 2*lda);
        float4 w3 = *(const float4*)(wp + 3*lda);
        float4 h4 = *(const float4*)(hp);
        hp += 4; wp += 4*(size_t)lda;
        acc.x = fmaf(w0.x,h4.x,acc.x); acc.y = fmaf(w0.y,h4.x,acc.y); acc.z = fmaf(w0.z,h4.x,acc.z); acc.w = fmaf(w0.w,h4.x,acc.w);
        acc.x = fmaf(w1.x,h4.y,acc.x); acc.y = fmaf(w1.y,h4.y,acc.y); acc.z = fmaf(w1.z,h4.y,acc.z); acc.w = fmaf(w1.w,h4.y,acc.w);
        acc.x = fmaf(w2.x,h4.z,acc.x); acc.y = fmaf(w2.y,h4.z,acc.y); acc.z = fmaf(w2.z,h4.z,acc.z); acc.w = fmaf(w2.w,h4.z,acc.w);
        acc.x = fmaf(w3.x,h4.w,acc.x); acc.y = fmaf(w3.y,h4.w,acc.y); acc.z = fmaf(w3.z,h4.w,acc.z); acc.w = fmaf(w3.w,h4.w,acc.w);
      }
      *(float4*)(scratch + kp*260 + (bl*16+jq)*4) = acc;
      __syncthreads();
      if (tid < 256){
        const int bl2 = tid>>6, jl = tid&63;
        float s = 0.f;
        #pragma unroll
        for (int kp2=0;kp2<8;kp2++) s += scratch[kp2*260 + bl2*64 + jl];
        int jcol = jbaseA + jl;
        int jout = jt*64 + jl;
        float v;
        if (modeA==0) v = s + P.dec_att_b[jcol];
        else if (modeA==1) v = sigf(s + P.f_beta_b[jcol]);
        else v = s;
        M1[(bg*4+bl2)*4096 + jout] = v;
      }
      __syncthreads();
    }
    gg.sync();

    // ---- Phase B: scores[row] = relu(att1[row]+att2[b]) . faW + fab
    {
      const float fab = P.full_att_b[0];
      const int w = (bx<<3) | wid;      // [0,2048)
      for (int row = w; row < NB*NP; row += 2048){
        int b = row / 196;
        const float* a1 = P.att1 + (size_t)row*NE;
        const float* a2 = M1 + b*4096;
        float s = 0.f;
        #pragma unroll
        for (int i=0;i<4;i++){
          int e = i*256 + lane*4;
          float4 x = *(const float4*)(a1 + e);
          float4 y = *(const float4*)(a2 + e);
          float4 fw = *(const float4*)(P.full_att_W + e);
          float v;
          v = x.x + y.x; v = v>0.f?v:0.f; s = fmaf(v, fw.x, s);
          v = x.y + y.y; v = v>0.f?v:0.f; s = fmaf(v, fw.y, s);
          v = x.z + y.z; v = v>0.f?v:0.f; s = fmaf(v, fw.z, s);
          v = x.w + y.w; v = v>0.f?v:0.f; s = fmaf(v, fw.w, s);
        }
        #pragma unroll
        for (int off=32; off; off>>=1) s += __shfl_down(s, off, 64);
        if (lane == 0) scores[row] = s + fab;
      }
    }
    gg.sync();

    // ---- Phase C: softmax (redundant per chunk) + awe chunk of 64 e; aweg = gate + awe
    {
      float* sc   = scratch;            // [0,256)
      float* red2 = scratch + 256;      // [256,512)
      float* redp = scratch + 512;      // 8*68 = 544
      const int b = bx >> 4, ch = bx & 15;
      const int ob = sortind[b];
      float v = (tid < NP) ? scores[b*NP + tid] : -1e30f;
      if (tid < NP) sc[tid] = v;
      if (tid < 256) red2[tid] = v;
      __syncthreads();
      for (int s=128; s; s>>=1){ if (tid < s) red2[tid] = fmaxf(red2[tid], red2[tid+s]); __syncthreads(); }
      const float mx = red2[0];
      __syncthreads();
      float ex = (tid < NP) ? expf(sc[tid] - mx) : 0.f;
      if (tid < NP) sc[tid] = ex;
      if (tid < 256) red2[tid] = ex;
      __syncthreads();
      for (int s=128; s; s>>=1){ if (tid < s) red2[tid] += red2[tid+s]; __syncthreads(); }
      const float inv = 1.f / red2[0];
      __syncthreads();
      if (tid < NP) sc[tid] *= inv;     // alpha
      __syncthreads();
      const int el = tid & 63, pp = tid >> 6;   // 64 e x 8 p-parts
      const int e = ch*64 + el;
      const float* ep = P.enc + (size_t)ob*NP*NE + e;
      float part = 0.f;
      for (int p = pp; p < NP; p += 8)
        part = fmaf(ep[(size_t)p*NE], sc[p], part);
      redp[pp*68 + el] = part;
      __syncthreads();
      if (tid < 64){
        float aw = 0.f;
        #pragma unroll
        for (int q=0;q<8;q++) aw += redp[q*68 + tid];
        int e2 = ch*64 + tid;
        aweg[b*NE + e2] = M1[b*4096 + 1024 + e2] + aw;
      }
      if (ch == 0 && tid < NP){
        P.out[OFF_ALPHAS + (size_t)b*NT*NP + (size_t)tt*NP + tid] = (declen[b] > tt) ? sc[tid] : 0.f;
      }
      __syncthreads();
    }
    gg.sync();

    // ---- Phase D: gsum[B][j] = preih + gates_h + aweg . Wih2
    {
      float* ags  = scratch;            // 4*1040 = 4160
      float* redd = scratch + 4160;     // 16*132 = 2112 (total 6272)
      const float* src = aweg + (bg*4)*NE;
      #pragma unroll
      for (int i=0;i<2;i++){
        int idx = tid + i*512;          // float4 index in [0,1024)
        float4 v4 = ((const float4*)src)[idx];
        int bl = idx >> 8, k = (idx & 255)*4;
        *(float4*)(ags + bl*1040 + k) = v4;
      }
      __syncthreads();
      const int j0 = jt*32;
      const int jq = tid & 7, bl = (tid>>3)&3, kp = tid>>5;
      const float* wp = Wih2 + (size_t)(kp*64)*NG + j0 + jq*4;
      const float* ap = ags + bl*1040 + kp*64;
      float4 acc = make_float4(0.f,0.f,0.f,0.f);
      #pragma unroll
      for (int k4=0;k4<16;k4++){
        float4 w0 = *(const float4*)(wp);
        float4 w1 = *(const float4*)(wp + NG);
        float4 w2 = *(const float4*)(wp + 2*NG);
        float4 w3 = *(const float4*)(wp + 3*NG);
        float4 a4 = *(const float4*)(ap);
        ap += 4; wp += 4*(size_t)NG;
        acc.x = fmaf(w0.x,a4.x,acc.x); acc.y = fmaf(w0.y,a4.x,acc.y); acc.z = fmaf(w0.z,a4.x,acc.z); acc.w = fmaf(w0.w,a4.x,acc.w);
        acc.x = fmaf(w1.x,a4.y,acc.x); acc.y = fmaf(w1.y,a4.y,acc.y); acc.z = fmaf(w1.z,a4.y,acc.z); acc.w = fmaf(w1.w,a4.y,acc.w);
        acc.x = fmaf(w2.x,a4.z,acc.x); acc.y = fmaf(w2.y,a4.z,acc.y); acc.z = fmaf(w2.z,a4.z,acc.z); acc.w = fmaf(w2.w,a4.z,acc.w);
        acc.x = fmaf(w3.x,a4.w,acc.x); acc.y = fmaf(w3.y,a4.w,acc.y); acc.z = fmaf(w3.z,a4.w,acc.z); acc.w = fmaf(w3.w,a4.w,acc.w);
      }
      *(float4*)(redd + kp*132 + (bl*8+jq)*4) = acc;
      __syncthreads();
      if (tid < 128){
        const int bl2 = tid>>5, jl = tid&31;
        float s = 0.f;
        #pragma unroll
        for (int kp2=0;kp2<16;kp2++) s += redd[kp2*132 + bl2*32 + jl];
        int j = j0 + jl;
        int B = bg*4 + bl2;
        P.gsum[B*NG + j] = s + P.preih[(size_t)(tt*NB + B)*NG + j] + M1[B*4096 + 2048 + j];
      }
      __syncthreads();
    }
    gg.sync();
  }
}

extern "C" void kernel_launch(void* const* d_in, const int* in_sizes, int n_in,
                              void* d_out, int out_size, void* d_ws, size_t ws_size,
                              hipStream_t stream) {
  const float* encoder_out = (const float*)d_in[0];
  const float* enc_att_W   = (const float*)d_in[1];
  const float* enc_att_b   = (const float*)d_in[2];
  const float* dec_att_W   = (const float*)d_in[3];
  const float* dec_att_b   = (const float*)d_in[4];
  const float* full_att_W  = (const float*)d_in[5];
  const float* full_att_b  = (const float*)d_in[6];
  const float* emb         = (const float*)d_in[7];
  const float* W_ih        = (const float*)d_in[8];
  const float* b_ih        = (const float*)d_in[9];
  const float* W_hh        = (const float*)d_in[10];
  const float* b_hh        = (const float*)d_in[11];
  const float* init_h_W    = (const float*)d_in[12];
  const float* init_h_b    = (const float*)d_in[13];
  const float* init_c_W    = (const float*)d_in[14];
  const float* init_c_b    = (const float*)d_in[15];
  const float* f_beta_W    = (const float*)d_in[16];
  const float* f_beta_b    = (const float*)d_in[17];
  const float* fc_W        = (const float*)d_in[18];
  const float* fc_b        = (const float*)d_in[19];
  const int*   caps        = (const int*)d_in[20];
  const int*   caplen      = (const int*)d_in[21];
  (void)in_sizes; (void)n_in; (void)out_size; (void)ws_size;

  float* out  = (float*)d_out;
  float* wsf  = (float*)d_ws;
  int*   wsi  = (int*)d_ws;
  float* att1F  = out + OFF_ATT1;
  float* preihF = out + OFF_PREIH;
  float* gsumF  = out + OFF_GSUM;

  hipLaunchKernelGGL(k_sort, dim3(1), dim3(64), 0, stream, caplen, caps, wsi, out);
  hipLaunchKernelGGL(k_mean, dim3(64), dim3(256), 0, stream, encoder_out, wsi, wsf);
  hipLaunchKernelGGL(k_init, dim3(64), dim3(256), 0, stream, init_h_W, init_h_b, init_c_W, init_c_b, wsf);
  // att1 = enc_s @ enc_att_W + enc_att_b : M=3136, N=1024, K=1024
  hipLaunchKernelGGL(k_gemm, dim3(16,49), dim3(256), 0, stream,
                     encoder_out, enc_att_W, enc_att_b, (const float*)nullptr,
                     att1F, 3136, 1024, 1024, 0, wsi, caps);
  // pre_ih = embs @ W_ih[:512] + b_ih + b_hh : M=496, N=2048, K=512
  hipLaunchKernelGGL(k_gemm, dim3(32,8), dim3(256), 0, stream,
                     emb, W_ih, b_ih, b_hh,
                     preihF, 496, 2048, 512, 1, wsi, caps);

  ScanParams sp;
  sp.wsf = wsf; sp.wsi = wsi;
  sp.att1 = att1F; sp.preih = preihF; sp.gsum = gsumF;
  sp.dec_att_W = dec_att_W; sp.dec_att_b = dec_att_b;
  sp.f_beta_W = f_beta_W; sp.f_beta_b = f_beta_b;
  sp.W_hh = W_hh; sp.W_ih = W_ih;
  sp.full_att_W = full_att_W; sp.full_att_b = full_att_b;
  sp.enc = encoder_out; sp.out = out;
  void* args[] = { &sp };
  hipLaunchCooperativeKernel((void*)k_scan, dim3(NBLK), dim3(512), args, 0, stream);

  // predictions = h_hist @ fc_W + fc_b (masked) : M=496, N=10000, K=512
  hipLaunchKernelGGL(k_gemm, dim3(157,8), dim3(256), 0, stream,
                     wsf + WS_HHIST, fc_W, fc_b, (const float*)nullptr,
                     out, 496, 10000, 512, 2, wsi, caps);
}